// Round 1
// baseline (1171.962 us; speedup 1.0000x reference)
//
#include <hip/hip_runtime.h>
#include <hip/hip_bf16.h>

// Problem constants (fixed by the reference)
#define B_  2
#define S_  2048
#define D_  1024
#define H_  16
#define HD_ 64
constexpr int   BS    = B_ * S_;        // 4096 rows
constexpr float SCALE = 0.03125f;       // 1/sqrt(1024)

typedef __bf16 bf16x8 __attribute__((ext_vector_type(8)));
typedef float  f32x4  __attribute__((ext_vector_type(4)));

__device__ __forceinline__ ushort f2bs(float f) {
    // round-to-nearest-even fp32 -> bf16
    unsigned u = __builtin_bit_cast(unsigned, f);
    unsigned r = (u + 0x7fffu + ((u >> 16) & 1u)) >> 16;
    return (ushort)r;
}

__device__ __forceinline__ bf16x8 ld16(const ushort* p) {
    uint4 u = *(const uint4*)p;
    return __builtin_bit_cast(bf16x8, u);
}

__device__ __forceinline__ f32x4 mfma16(bf16x8 a, bf16x8 b, f32x4 c) {
    return __builtin_amdgcn_mfma_f32_16x16x32_bf16(a, b, c, 0, 0, 0);
}

// ---------------------------------------------------------------------------
// fp32 -> bf16 bulk convert
__global__ void cvt_bf16(const float* __restrict__ x, ushort* __restrict__ y, int n) {
    int i = (blockIdx.x * blockDim.x + threadIdx.x) * 4;
    if (i + 3 < n) {
        float4 v = *(const float4*)(x + i);
        ushort4 o = make_ushort4(f2bs(v.x), f2bs(v.y), f2bs(v.z), f2bs(v.w));
        *(ushort4*)(y + i) = o;
    }
}

// ---------------------------------------------------------------------------
// Weight transpose+convert: W [K][N] fp32 -> WT [N][K] bf16 (4 weights via z)
__global__ void wtrans(const float* __restrict__ Wq, const float* __restrict__ Wk,
                       const float* __restrict__ Wv, const float* __restrict__ Wo,
                       ushort* __restrict__ Tq, ushort* __restrict__ Tk,
                       ushort* __restrict__ Tv, ushort* __restrict__ To) {
    const float* W; ushort* T;
    switch (blockIdx.z) {
        case 0: W = Wq; T = Tq; break;
        case 1: W = Wk; T = Tk; break;
        case 2: W = Wv; T = Tv; break;
        default: W = Wo; T = To; break;
    }
    __shared__ float tile[32][33];
    int n0 = blockIdx.x * 32, k0 = blockIdx.y * 32;
    int tx = threadIdx.x, ty = threadIdx.y;   // (32, 8)
    #pragma unroll
    for (int i = 0; i < 4; i++)
        tile[ty + i * 8][tx] = W[(size_t)(k0 + ty + i * 8) * D_ + n0 + tx];
    __syncthreads();
    #pragma unroll
    for (int i = 0; i < 4; i++) {
        int n = ty + i * 8;
        T[(size_t)(n0 + n) * D_ + k0 + tx] = f2bs(tile[tx][n]);
    }
}

// ---------------------------------------------------------------------------
// bf16 GEMM: C[M=4096][N=1024] = A[M][K=1024] * BT[N][K]^T + bias (+relpos)
// 128x128 tile, BK=64, 4 waves of 64x64, 16x16x32 MFMA.
template <bool OUT_F32, bool RELPOS>
__global__ __launch_bounds__(256) void gemm_bt(
        const ushort* __restrict__ A, const ushort* __restrict__ BT,
        const float* __restrict__ bias,
        float* __restrict__ Cf, ushort* __restrict__ Cb,
        const int* __restrict__ clipPtr) {
    constexpr int K = D_, N = D_;
    __shared__ ushort As[128][72];   // +8 pad: 2-way-max bank aliasing on b128 reads
    __shared__ ushort Bs[128][72];
    int t = threadIdx.x;
    int m0 = blockIdx.y * 128, n0 = blockIdx.x * 128;
    int w = t >> 6, lane = t & 63, quad = lane >> 4, l16 = lane & 15;
    int wm = (w >> 1) * 64, wn = (w & 1) * 64;

    f32x4 acc[4][4];
    #pragma unroll
    for (int i = 0; i < 4; i++)
        #pragma unroll
        for (int j = 0; j < 4; j++) acc[i][j] = (f32x4){0.f, 0.f, 0.f, 0.f};

    int srow = t >> 3, scol = (t & 7) * 8;
    for (int k0 = 0; k0 < K; k0 += 64) {
        #pragma unroll
        for (int i = 0; i < 4; i++) {
            int r = srow + 32 * i;
            *(uint4*)&As[r][scol] = *(const uint4*)(A  + (size_t)(m0 + r) * K + k0 + scol);
            *(uint4*)&Bs[r][scol] = *(const uint4*)(BT + (size_t)(n0 + r) * K + k0 + scol);
        }
        __syncthreads();
        #pragma unroll
        for (int kk = 0; kk < 64; kk += 32) {
            bf16x8 af[4], bf[4];
            #pragma unroll
            for (int mi = 0; mi < 4; mi++) af[mi] = ld16(&As[wm + mi * 16 + l16][kk + quad * 8]);
            #pragma unroll
            for (int ni = 0; ni < 4; ni++) bf[ni] = ld16(&Bs[wn + ni * 16 + l16][kk + quad * 8]);
            #pragma unroll
            for (int mi = 0; mi < 4; mi++)
                #pragma unroll
                for (int ni = 0; ni < 4; ni++)
                    acc[mi][ni] = mfma16(af[mi], bf[ni], acc[mi][ni]);
        }
        __syncthreads();
    }

    float clipv = 0.f;
    if constexpr (RELPOS) clipv = (float)clipPtr[0];
    #pragma unroll
    for (int mi = 0; mi < 4; mi++) {
        #pragma unroll
        for (int r = 0; r < 4; r++) {
            int row = m0 + wm + mi * 16 + quad * 4 + r;
            int s = row & (S_ - 1);
            #pragma unroll
            for (int ni = 0; ni < 4; ni++) {
                int col = n0 + wn + ni * 16 + l16;
                float v = acc[mi][ni][r] + bias[col];
                if constexpr (RELPOS) {
                    float rp = (float)(col - s);
                    v += fminf(fmaxf(rp, -clipv), clipv);
                }
                if constexpr (OUT_F32) Cf[(size_t)row * N + col] = v;
                else                   Cb[(size_t)row * N + col] = f2bs(v);
            }
        }
    }
}

// ---------------------------------------------------------------------------
// V transpose per head: Vh[S][64] -> VT[64][S] (bf16), for PV B-fragments
__global__ void vtrans(const ushort* __restrict__ Vb, ushort* __restrict__ VT) {
    int kt = blockIdx.x, bh = blockIdx.y;
    const ushort* src = Vb + (size_t)bh * S_ * HD_;
    ushort* dst = VT + (size_t)bh * HD_ * S_;
    __shared__ ushort ts[64][65];
    int t = threadIdx.x;
    int k0 = kt * 64;
    int dc = (t & 31) * 2, kr = t >> 5;
    #pragma unroll
    for (int i = 0; i < 8; i++) {
        int k = kr + i * 8;
        uint v = *(const uint*)(src + (size_t)(k0 + k) * HD_ + dc);
        ts[k][dc]     = (ushort)(v & 0xffffu);
        ts[k][dc + 1] = (ushort)(v >> 16);
    }
    __syncthreads();
    int kc = (t & 31) * 2, dr = t >> 5;
    #pragma unroll
    for (int i = 0; i < 8; i++) {
        int d = dr + i * 8;
        uint lo = ts[kc][d], hi = ts[kc + 1][d];
        *(uint*)(dst + (size_t)d * S_ + k0 + kc) = lo | (hi << 16);
    }
}

// ---------------------------------------------------------------------------
// Pass 1: per-row softmax stats (m, Z) via online max/sum. One wave = 16 q rows.
__global__ __launch_bounds__(256) void attn_stats(
        const ushort* __restrict__ Qb, const ushort* __restrict__ Kb,
        const float* __restrict__ mask,
        float* __restrict__ mOut, float* __restrict__ zOut) {
    int h = blockIdx.x, qt = blockIdx.y, b = blockIdx.z;
    int t = threadIdx.x, w = t >> 6, lane = t & 63, quad = lane >> 4, l16 = lane & 15;
    size_t headoff = ((size_t)(b * H_) + h) * S_ * HD_;
    const ushort* Qh = Qb + headoff;
    const ushort* Kh = Kb + headoff;
    const float* mk = mask + (size_t)b * S_ * S_;
    int q0 = qt * 64 + w * 16;

    bf16x8 a0 = ld16(Qh + (size_t)(q0 + l16) * HD_ + quad * 8);
    bf16x8 a1 = ld16(Qh + (size_t)(q0 + l16) * HD_ + 32 + quad * 8);

    float mr[4], lr[4];
    #pragma unroll
    for (int r = 0; r < 4; r++) { mr[r] = -3.0e38f; lr[r] = 0.f; }

    for (int kc = 0; kc < S_; kc += 16) {
        bf16x8 b0 = ld16(Kh + (size_t)(kc + l16) * HD_ + quad * 8);
        bf16x8 b1 = ld16(Kh + (size_t)(kc + l16) * HD_ + 32 + quad * 8);
        f32x4 dm = (f32x4){0.f, 0.f, 0.f, 0.f};
        dm = mfma16(a0, b0, dm);
        dm = mfma16(a1, b1, dm);
        #pragma unroll
        for (int r = 0; r < 4; r++) {
            int qrow = q0 + quad * 4 + r;
            float s = dm[r] * SCALE * mk[(size_t)qrow * S_ + kc + l16];
            if (s <= mr[r]) {
                lr[r] += __expf(s - mr[r]);
            } else {
                lr[r] = lr[r] * __expf(mr[r] - s) + 1.f;
                mr[r] = s;
            }
        }
    }
    // reduce over the 16 lanes (columns) of each quad group
    #pragma unroll
    for (int off = 1; off < 16; off <<= 1) {
        #pragma unroll
        for (int r = 0; r < 4; r++) {
            float mo = __shfl_xor(mr[r], off, 64);
            float lo = __shfl_xor(lr[r], off, 64);
            float mn = fmaxf(mr[r], mo);
            lr[r] = lr[r] * __expf(mr[r] - mn) + lo * __expf(mo - mn);
            mr[r] = mn;
        }
    }
    if (l16 == 0) {
        size_t base = ((size_t)(b * H_) + h) * S_;
        #pragma unroll
        for (int r = 0; r < 4; r++) {
            mOut[base + q0 + quad * 4 + r] = mr[r];
            zOut[base + q0 + quad * 4 + r] = lr[r];
        }
    }
}

// ---------------------------------------------------------------------------
// Pass 2: recompute scores, write attn (fp32, full matrix), accumulate AV.
__global__ __launch_bounds__(256) void attn_av(
        const ushort* __restrict__ Qb, const ushort* __restrict__ Kb,
        const ushort* __restrict__ VT, const float* __restrict__ mask,
        const float* __restrict__ mIn, const float* __restrict__ zIn,
        float* __restrict__ attnOut, ushort* __restrict__ AVb) {
    __shared__ ushort plds[4][16][32];   // per-wave P tile (D-layout -> A-layout)
    int h = blockIdx.x, qt = blockIdx.y, b = blockIdx.z;
    int t = threadIdx.x, w = t >> 6, lane = t & 63, quad = lane >> 4, l16 = lane & 15;
    size_t headoff = ((size_t)(b * H_) + h) * S_ * HD_;
    const ushort* Qh = Qb + headoff;
    const ushort* Kh = Kb + headoff;
    const ushort* VTh = VT + ((size_t)(b * H_) + h) * HD_ * S_;
    const float* mk = mask + (size_t)b * S_ * S_;
    float* aout = attnOut + ((size_t)(b * H_) + h) * S_ * S_;
    size_t sbase = ((size_t)(b * H_) + h) * S_;
    int q0 = qt * 64 + w * 16;

    float mrow[4], iz[4];
    #pragma unroll
    for (int r = 0; r < 4; r++) {
        mrow[r] = mIn[sbase + q0 + quad * 4 + r];
        iz[r]   = 1.0f / zIn[sbase + q0 + quad * 4 + r];
    }
    bf16x8 a0 = ld16(Qh + (size_t)(q0 + l16) * HD_ + quad * 8);
    bf16x8 a1 = ld16(Qh + (size_t)(q0 + l16) * HD_ + 32 + quad * 8);

    f32x4 av0 = (f32x4){0.f,0.f,0.f,0.f}, av1 = av0, av2 = av0, av3 = av0;

    for (int kc = 0; kc < S_; kc += 32) {
        bf16x8 k00 = ld16(Kh + (size_t)(kc + l16) * HD_ + quad * 8);
        bf16x8 k01 = ld16(Kh + (size_t)(kc + l16) * HD_ + 32 + quad * 8);
        bf16x8 k10 = ld16(Kh + (size_t)(kc + 16 + l16) * HD_ + quad * 8);
        bf16x8 k11 = ld16(Kh + (size_t)(kc + 16 + l16) * HD_ + 32 + quad * 8);
        f32x4 d0 = (f32x4){0.f,0.f,0.f,0.f}, d1 = d0;
        d0 = mfma16(a0, k00, d0); d0 = mfma16(a1, k01, d0);
        d1 = mfma16(a0, k10, d1); d1 = mfma16(a1, k11, d1);
        #pragma unroll
        for (int r = 0; r < 4; r++) {
            int qrow = q0 + quad * 4 + r;
            float s0 = d0[r] * SCALE * mk[(size_t)qrow * S_ + kc + l16];
            float s1 = d1[r] * SCALE * mk[(size_t)qrow * S_ + kc + 16 + l16];
            float p0 = __expf(s0 - mrow[r]) * iz[r];
            float p1 = __expf(s1 - mrow[r]) * iz[r];
            aout[(size_t)qrow * S_ + kc + l16]      = p0;
            aout[(size_t)qrow * S_ + kc + 16 + l16] = p1;
            plds[w][quad * 4 + r][l16]      = f2bs(p0);
            plds[w][quad * 4 + r][16 + l16] = f2bs(p1);
        }
        // intra-wave LDS RAW: compiler inserts lgkmcnt wait; no barrier needed
        bf16x8 pa = ld16(&plds[w][l16][quad * 8]);
        bf16x8 v0 = ld16(VTh + (size_t)(0 * 16 + l16) * S_ + kc + quad * 8);
        bf16x8 v1 = ld16(VTh + (size_t)(1 * 16 + l16) * S_ + kc + quad * 8);
        bf16x8 v2 = ld16(VTh + (size_t)(2 * 16 + l16) * S_ + kc + quad * 8);
        bf16x8 v3 = ld16(VTh + (size_t)(3 * 16 + l16) * S_ + kc + quad * 8);
        av0 = mfma16(pa, v0, av0);
        av1 = mfma16(pa, v1, av1);
        av2 = mfma16(pa, v2, av2);
        av3 = mfma16(pa, v3, av3);
    }
    ushort* avh = AVb + headoff;
    #pragma unroll
    for (int r = 0; r < 4; r++) {
        int qrow = q0 + quad * 4 + r;
        avh[(size_t)qrow * HD_ + 0 + l16]  = f2bs(av0[r]);
        avh[(size_t)qrow * HD_ + 16 + l16] = f2bs(av1[r]);
        avh[(size_t)qrow * HD_ + 32 + l16] = f2bs(av2[r]);
        avh[(size_t)qrow * HD_ + 48 + l16] = f2bs(av3[r]);
    }
}

// ---------------------------------------------------------------------------
extern "C" void kernel_launch(void* const* d_in, const int* in_sizes, int n_in,
                              void* d_out, int out_size, void* d_ws, size_t ws_size,
                              hipStream_t stream) {
    const float* inputs  = (const float*)d_in[0];
    const float* context = (const float*)d_in[1];
    const float* mask    = (const float*)d_in[2];
    const float* Wq = (const float*)d_in[3];
    const float* bq = (const float*)d_in[4];
    const float* Wk = (const float*)d_in[5];
    const float* bk = (const float*)d_in[6];
    const float* Wv = (const float*)d_in[7];
    const float* bv = (const float*)d_in[8];
    const float* Wo = (const float*)d_in[9];
    const float* bo = (const float*)d_in[10];
    const int*   clip = (const int*)d_in[11];

    float* out  = (float*)d_out;
    float* attn = out + (size_t)B_ * S_ * D_;

    // workspace layout (bf16 buffers as ushort)
    ushort* Xb  = (ushort*)d_ws;          // inputs bf16   [4096][1024]
    ushort* Cb  = Xb  + (size_t)BS * D_;  // context bf16
    ushort* WqT = Cb  + (size_t)BS * D_;  // W^T bf16 [1024][1024] x4
    ushort* WkT = WqT + (size_t)D_ * D_;
    ushort* WvT = WkT + (size_t)D_ * D_;
    ushort* WoT = WvT + (size_t)D_ * D_;
    ushort* Qb  = WoT + (size_t)D_ * D_;  // q,k,v bf16 [B][S][D]
    ushort* Kb  = Qb  + (size_t)BS * D_;
    ushort* Vb  = Kb  + (size_t)BS * D_;
    ushort* VT  = Vb  + (size_t)BS * D_;  // per-head V^T [B*H][64][2048]
    ushort* AVb = VT  + (size_t)BS * D_;  // attention output, head-flat layout
    float* mStat = (float*)(AVb + (size_t)BS * D_);  // [B*H*S]
    float* zStat = mStat + (size_t)B_ * H_ * S_;

    int nElem = BS * D_;  // 4194304

    cvt_bf16<<<nElem / (256 * 4), 256, 0, stream>>>(inputs,  Xb, nElem);
    cvt_bf16<<<nElem / (256 * 4), 256, 0, stream>>>(context, Cb, nElem);
    wtrans<<<dim3(32, 32, 4), dim3(32, 8), 0, stream>>>(Wq, Wk, Wv, Wo, WqT, WkT, WvT, WoT);

    gemm_bt<false, true ><<<dim3(8, 32), 256, 0, stream>>>(Xb, WqT, bq, nullptr, Qb, clip);
    gemm_bt<false, false><<<dim3(8, 32), 256, 0, stream>>>(Cb, WkT, bk, nullptr, Kb, clip);
    gemm_bt<false, true ><<<dim3(8, 32), 256, 0, stream>>>(Cb, WvT, bv, nullptr, Vb, clip);

    vtrans<<<dim3(32, 32), 256, 0, stream>>>(Vb, VT);

    attn_stats<<<dim3(H_, S_ / 64, B_), 256, 0, stream>>>(Qb, Kb, mask, mStat, zStat);
    attn_av<<<dim3(H_, S_ / 64, B_), 256, 0, stream>>>(Qb, Kb, VT, mask, mStat, zStat, attn, AVb);

    gemm_bt<true, false><<<dim3(8, 32), 256, 0, stream>>>(AVb, WoT, bo, out, nullptr, clip);
}